// Round 1
// baseline (776.459 us; speedup 1.0000x reference)
//
#include <hip/hip_runtime.h>
#include <hip/hip_bf16.h>
#include <stdint.h>

// Problem dims
#define BATCH 256
#define SEQ   512
#define INDIM 64
#define H     128
#define RB    4               // batch rows per tile (valid C-rows at quad*4, r=0)
#define NTILE (BATCH / RB)    // 64 batch tiles per layer
#define NPAIR (NTILE / 2)     // 32 blocks per layer, 2 tiles per block
#define CH    16              // pipeline handoff chunk (steps)
#define NCH   (SEQ / CH)

using short8  = __attribute__((ext_vector_type(8))) short;  // 8 bf16 MFMA A/B frag
using float4v = __attribute__((ext_vector_type(4))) float;  // MFMA C/D frag

#define LOG2E 1.4426950408889634f

__device__ __forceinline__ unsigned short f2bf(float f) {
    union { float f; uint32_t u; } v; v.f = f;
    uint32_t u = v.u;
    return (unsigned short)((u + 0x7FFFu + ((u >> 16) & 1u)) >> 16); // RNE
}

__device__ __forceinline__ float fast_exp2(float x) {
#if __has_builtin(__builtin_amdgcn_exp2f)
    return __builtin_amdgcn_exp2f(x);
#else
    return __expf(x * 0.6931471805599453f);
#endif
}
__device__ __forceinline__ float fast_rcp(float x) {
#if __has_builtin(__builtin_amdgcn_rcpf)
    return __builtin_amdgcn_rcpf(x);
#else
    return 1.f / x;
#endif
}
__device__ __forceinline__ float sigmoid_fast(float x) {
    return fast_rcp(1.f + fast_exp2(-LOG2E * x));
}
__device__ __forceinline__ float tanh_fast(float x) {
    return fmaf(-2.f, fast_rcp(1.f + fast_exp2((2.f * LOG2E) * x)), 1.f);
}

// In-step barrier: LDS ordering only (lgkmcnt). Global prefetch loads and
// producer h-stores stay in flight across it. Full __syncthreads (vmcnt
// drain) only at chunk boundaries.
__device__ __forceinline__ void light_barrier() {
    asm volatile("s_waitcnt lgkmcnt(0)\n\ts_barrier" ::: "memory");
}

// ---------------- x fp32 -> bf16 convert (+ flag zeroing) ----------------
__global__ void conv_x_kernel(const float* __restrict__ x,
                              unsigned short* __restrict__ xb, int n4,
                              int* __restrict__ flags) {
    int i = blockIdx.x * blockDim.x + threadIdx.x;
    if (blockIdx.x == 0 && threadIdx.x < NPAIR) flags[threadIdx.x] = 0;
    if (i >= n4) return;
    float4 f = ((const float4*)x)[i];
    ushort4 o;
    o.x = f2bf(f.x); o.y = f2bf(f.y); o.z = f2bf(f.z); o.w = f2bf(f.w);
    ((ushort4*)xb)[i] = o;
}

// ---------------- fused 2-layer pipelined LSTM + head ----------------
// 64 blocks x 512 threads. Blocks 0..31: layer0 (producer), 32..63: layer1
// (consumer), paired on a PAIR of batch tiles (2*pt, 2*pt+1). Each wave
// interleaves TWO independent LSTM instances (tiles A and B) that share the
// weight registers; tile B's MFMAs/activations fill tile A's latency stalls
// (ds_read ~120cy, MFMA dep chains, serial sigmoid/tanh chain), which were
// ~65% of the step time in the single-tile version (MfmaUtil 22%).
// Single chained accumulator per tile: acc = bias(elem0) -> x-MFMAs ->
// h-MFMAs; x-MFMAs issue at step start and cover the h ds_read latency.
// Depth-1 x prefetch: xf consumed at step start, reloaded immediately after
// (next use is one full dual-step away, ~700cy > LLC latency).
// CRITICAL (R5 lesson): every per-thread register array (xfA/xfB, accA/accB,
// frags) is indexed ONLY with compile-time constants (unrolled loops,
// statically-named A/B copies). Dynamic VGPR-array indexing demotes to
// scratch (65x regression). LDS may be dynamically indexed; VGPR arrays not.
template<int KIN, bool IS_PROD>
__device__ __forceinline__ void lstm_body(
    const unsigned short* __restrict__ xin,  // [BATCH][SEQ][KIN] bf16
    const float* __restrict__ Wih,           // [4H][KIN]
    const float* __restrict__ Whh,           // [4H][H]
    const float* __restrict__ b_ih, const float* __restrict__ b_hh,
    unsigned short* __restrict__ outseq,     // producer: [BATCH][SEQ][H] bf16
    const float* __restrict__ W1, const float* __restrict__ b1,
    const float* __restrict__ W2, const float* __restrict__ b2,
    float* __restrict__ out,                 // consumer: [BATCH][3]
    int* flag, int pt)
{
    constexpr int KT  = KIN / 32;
    constexpr int PAD = 132;                 // 66 dwords == 2 mod 32 -> 2-way (free) aliasing
    const int lane = threadIdx.x & 63;
    const int quad = lane >> 4;
    const int l16  = lane & 15;
    const int b0A  = (2 * pt) * RB;
    const int b0B  = (2 * pt + 1) * RB;
    const int cell = (threadIdx.x >> 6) * 16 + l16;
    const int arow = l16 & 12;               // LDS h row this lane reads (4-lane broadcast)

    __shared__ short hbA[2][16][PAD];        // tile A h double buffer
    __shared__ short hbB[2][16][PAD];        // tile B h double buffer
    __shared__ float hl[2][RB][128];         // fp32 h_last per tile (head input)
    __shared__ float mid[2][RB][65];
    for (int i = threadIdx.x; i < 2 * 16 * PAD; i += 512) {
        ((short*)hbA)[i] = 0;
        ((short*)hbB)[i] = 0;
    }

    // ---- weight fragments (loaded once, fp32->bf16, persist in registers,
    //      SHARED by both tiles) ----
    short8 whh_f[4][4];
    short8 wih_f[4][KT];
    float  bias[4];
#pragma unroll
    for (int tT = 0; tT < 4; tT++) {
        const int n = tT * 128 + cell;
#pragma unroll
        for (int kt = 0; kt < 4; kt++) {
            const float* p = Whh + (size_t)n * H + kt * 32 + quad * 8;
            float4 f0 = *(const float4*)p;
            float4 f1 = *(const float4*)(p + 4);
            short8 s;
            s[0]=f2bf(f0.x); s[1]=f2bf(f0.y); s[2]=f2bf(f0.z); s[3]=f2bf(f0.w);
            s[4]=f2bf(f1.x); s[5]=f2bf(f1.y); s[6]=f2bf(f1.z); s[7]=f2bf(f1.w);
            whh_f[tT][kt] = s;
        }
#pragma unroll
        for (int kt = 0; kt < KT; kt++) {
            const float* p = Wih + (size_t)n * KIN + kt * 32 + quad * 8;
            float4 f0 = *(const float4*)p;
            float4 f1 = *(const float4*)(p + 4);
            short8 s;
            s[0]=f2bf(f0.x); s[1]=f2bf(f0.y); s[2]=f2bf(f0.z); s[3]=f2bf(f0.w);
            s[4]=f2bf(f1.x); s[5]=f2bf(f1.y); s[6]=f2bf(f1.z); s[7]=f2bf(f1.w);
            wih_f[tT][kt] = s;
        }
        bias[tT] = b_ih[n] + b_hh[n];
    }

    float c0A = 0.f, c0B = 0.f;              // each lane's cell state per tile

    const unsigned short* xpA = xin + ((size_t)(b0A + (l16 >> 2)) * SEQ) * KIN + quad * 8;
    const unsigned short* xpB = xin + ((size_t)(b0B + (l16 >> 2)) * SEQ) * KIN + quad * 8;
    unsigned short* opA = nullptr;
    unsigned short* opB = nullptr;
    if (IS_PROD) {
        opA = outseq + ((size_t)(b0A + quad) * SEQ) * H + cell;
        opB = outseq + ((size_t)(b0B + quad) * SEQ) * H + cell;
    }

    short8  xfA[KT], xfB[KT];                // depth-1 x buffers (static names)
    float4v accA[4], accB[4];                // persistent accs; elem0 reset/step
#pragma unroll
    for (int tT = 0; tT < 4; tT++) {
        accA[tT] = (float4v){bias[tT], bias[tT], bias[tT], bias[tT]};
        accB[tT] = (float4v){bias[tT], bias[tT], bias[tT], bias[tT]};
    }
    __syncthreads();                         // hbuf zero-init visible

    // One dual step: advances BOTH tiles by one timestep, one barrier.
    // Elements 1..3 of acc are never read; they accumulate bounded junk
    // (|.| < ~2500 over 512 steps, fp32-safe) so we only reset elem 0.
    auto dualstep = [&](int t, int CUR, bool doPre) __attribute__((always_inline)) {
        short8 haA[4], haB[4];
#pragma unroll
        for (int kt = 0; kt < 4; kt++) {
            haA[kt] = *(const short8*)&hbA[CUR][arow][kt * 32 + quad * 8];
            haB[kt] = *(const short8*)&hbB[CUR][arow][kt * 32 + quad * 8];
        }
        // x-projection first (xf ready): covers the ds_read latency above
#pragma unroll
        for (int tT = 0; tT < 4; tT++) {
            accA[tT][0] = bias[tT];
            accB[tT][0] = bias[tT];
        }
#pragma unroll
        for (int tT = 0; tT < 4; tT++)
#pragma unroll
            for (int kt = 0; kt < KT; kt++) {
                accA[tT] = __builtin_amdgcn_mfma_f32_16x16x32_bf16(xfA[kt], wih_f[tT][kt], accA[tT], 0, 0, 0);
                accB[tT] = __builtin_amdgcn_mfma_f32_16x16x32_bf16(xfB[kt], wih_f[tT][kt], accB[tT], 0, 0, 0);
            }
        // reload xf for t+1 (WAR after the MFMAs consumed them)
        if (doPre) {
            const unsigned short* pA = xpA + (size_t)(t + 1) * KIN;
            const unsigned short* pB = xpB + (size_t)(t + 1) * KIN;
#pragma unroll
            for (int kt = 0; kt < KT; kt++) {
                xfA[kt] = *(const short8*)(pA + kt * 32);
                xfB[kt] = *(const short8*)(pB + kt * 32);
            }
        }
        // recurrent projection
#pragma unroll
        for (int tT = 0; tT < 4; tT++)
#pragma unroll
            for (int kt = 0; kt < 4; kt++) {
                accA[tT] = __builtin_amdgcn_mfma_f32_16x16x32_bf16(haA[kt], whh_f[tT][kt], accA[tT], 0, 0, 0);
                accB[tT] = __builtin_amdgcn_mfma_f32_16x16x32_bf16(haB[kt], whh_f[tT][kt], accB[tT], 0, 0, 0);
            }
        float gA0 = accA[0][0], gA1 = accA[1][0], gA2 = accA[2][0], gA3 = accA[3][0];
        float gB0 = accB[0][0], gB1 = accB[1][0], gB2 = accB[2][0], gB3 = accB[3][0];

        // two independent activation chains; compiler interleaves them to
        // pack the transcendental pipe
        float siA = sigmoid_fast(gA0);
        float siB = sigmoid_fast(gB0);
        float sfA = sigmoid_fast(gA1);
        float sfB = sigmoid_fast(gB1);
        float tgA = tanh_fast(gA2);
        float tgB = tanh_fast(gB2);
        float soA = sigmoid_fast(gA3);
        float soB = sigmoid_fast(gB3);
        c0A = fmaf(sfA, c0A, siA * tgA);
        c0B = fmaf(sfB, c0B, siB * tgB);
        float hA = soA * tanh_fast(c0A);
        float hB = soB * tanh_fast(c0B);
        const unsigned short hbfA = f2bf(hA);
        const unsigned short hbfB = f2bf(hB);
        hbA[CUR ^ 1][quad * 4][cell] = (short)hbfA;
        hbB[CUR ^ 1][quad * 4][cell] = (short)hbfB;
        if (IS_PROD) {
            *opA = hbfA; opA += H;           // fire-and-forget; drained at chunk end
            *opB = hbfB; opB += H;
        } else if (t == SEQ - 1) {
            hl[0][quad][cell] = hA;
            hl[1][quad][cell] = hB;
        }
        light_barrier();                     // LDS-only: loads/stores stay in flight
    };

    for (int ch = 0; ch < NCH; ch++) {
        const int t0 = ch * CH;
        if (!IS_PROD) {
            if (threadIdx.x == 0) {
                while (__hip_atomic_load(flag, __ATOMIC_RELAXED, __HIP_MEMORY_SCOPE_AGENT) <= ch)
                    __builtin_amdgcn_s_sleep(2);
                (void)__hip_atomic_load(flag, __ATOMIC_ACQUIRE, __HIP_MEMORY_SCOPE_AGENT);
            }
            __syncthreads();
        }
        // chunk fill: consumer every chunk (x not available across the flag);
        // producer only once (its depth-1 reload chain runs across chunks)
        if (!IS_PROD || ch == 0) {
            const unsigned short* pA = xpA + (size_t)t0 * KIN;
            const unsigned short* pB = xpB + (size_t)t0 * KIN;
#pragma unroll
            for (int kt = 0; kt < KT; kt++) {
                xfA[kt] = *(const short8*)(pA + kt * 32);
                xfB[kt] = *(const short8*)(pB + kt * 32);
            }
        }

#pragma unroll 1
        for (int i = 0; i < CH; i += 2) {
            const int t = t0 + i;
            const bool pre0 = IS_PROD ? (t + 1 < SEQ) : (i + 1 < CH);
            const bool pre1 = IS_PROD ? (t + 2 < SEQ) : (i + 2 < CH);
            dualstep(t,     0, pre0);        // even -> reads hb*[0], writes hb*[1]
            dualstep(t + 1, 1, pre1);        // odd  -> reads hb*[1], writes hb*[0]
        }
        __syncthreads();                     // vmcnt drain (producer stores) + boundary
        if (IS_PROD && threadIdx.x == 0)
            __hip_atomic_fetch_add(flag, 1, __ATOMIC_RELEASE, __HIP_MEMORY_SCOPE_AGENT);
    }

    if (!IS_PROD) {
        // ---- MLP head: 512 threads = 2 tiles x 4 rows x 64 cols
        const int tl  = threadIdx.x >> 8;    // 0: tile A, 1: tile B (wave-uniform)
        const int q   = threadIdx.x & 255;
        const int b0t = tl ? b0B : b0A;
        {
            const int row = q >> 6, j = q & 63;
            float s = b1[j];
            const float* wr = W1 + (size_t)j * 128;
#pragma unroll 8
            for (int k = 0; k < 128; k++) s = fmaf(hl[tl][row][k], wr[k], s);
            mid[tl][row][j] = fmaxf(s, 0.f);
        }
        __syncthreads();
        if (q < RB * 3) {
            const int row = q / 3, k = q - row * 3;
            float o = b2[k];
            const float* wr = W2 + (size_t)k * 64;
#pragma unroll 8
            for (int j = 0; j < 64; j++) o = fmaf(mid[tl][row][j], wr[j], o);
            out[(size_t)(b0t + row) * 3 + k] = o;
        }
    }
}

__global__ __launch_bounds__(512, 2)
void lstm_fused_kernel(const unsigned short* __restrict__ xb,
                       const float* __restrict__ Wih0, const float* __restrict__ Whh0,
                       const float* __restrict__ bih0, const float* __restrict__ bhh0,
                       const float* __restrict__ Wih1, const float* __restrict__ Whh1,
                       const float* __restrict__ bih1, const float* __restrict__ bhh1,
                       unsigned short* __restrict__ h0sq,
                       const float* __restrict__ W1, const float* __restrict__ b1,
                       const float* __restrict__ W2, const float* __restrict__ b2,
                       float* __restrict__ out,
                       int* __restrict__ flags)
{
    const int pt = blockIdx.x & (NPAIR - 1);
    if (blockIdx.x < NPAIR)
        lstm_body<64,  true >(xb,   Wih0, Whh0, bih0, bhh0, h0sq,
                              W1, b1, W2, b2, out, flags + pt, pt);
    else
        lstm_body<128, false>(h0sq, Wih1, Whh1, bih1, bhh1, nullptr,
                              W1, b1, W2, b2, out, flags + pt, pt);
}

extern "C" void kernel_launch(void* const* d_in, const int* in_sizes, int n_in,
                              void* d_out, int out_size, void* d_ws, size_t ws_size,
                              hipStream_t stream) {
    const float* x     = (const float*)d_in[0];
    const float* W_ih0 = (const float*)d_in[1];
    const float* W_hh0 = (const float*)d_in[2];
    const float* b_ih0 = (const float*)d_in[3];
    const float* b_hh0 = (const float*)d_in[4];
    const float* W_ih1 = (const float*)d_in[5];
    const float* W_hh1 = (const float*)d_in[6];
    const float* b_ih1 = (const float*)d_in[7];
    const float* b_hh1 = (const float*)d_in[8];
    const float* W1    = (const float*)d_in[9];
    const float* b1    = (const float*)d_in[10];
    const float* W2    = (const float*)d_in[11];
    const float* b2    = (const float*)d_in[12];
    float* out = (float*)d_out;

    // workspace: xb bf16[256*512*64] @0 (16 MB); h0sq bf16[256*512*128] @16 MB (32 MB); flags @48 MB
    char* ws = (char*)d_ws;
    unsigned short* xb    = (unsigned short*)ws;
    unsigned short* h0sq  = (unsigned short*)(ws + 16777216);
    int*            flags = (int*)(ws + 50331648);

    conv_x_kernel<<<8192, 256, 0, stream>>>(x, xb, (BATCH * SEQ * INDIM) / 4, flags);
    lstm_fused_kernel<<<2 * NPAIR, 512, 0, stream>>>(xb, W_ih0, W_hh0, b_ih0, b_hh0,
                                                     W_ih1, W_hh1, b_ih1, b_hh1,
                                                     h0sq, W1, b1, W2, b2, out, flags);
}